// Round 2
// baseline (1353.199 us; speedup 1.0000x reference)
//
#include <hip/hip_runtime.h>

// Physics_Attention_Irregular_Mesh — round 1: f32 inputs/outputs (round-0 NaN
// root cause: inputs are float32 per reference, were misread as bf16).
// B=4, N=16384, DIM=256, H=8, D=64, G=32, inner=512.
// Pipeline:
//   k0   : fold Wxs[256x256] = per-head Wx_h @ Wslice (f32), bxs
//   gemm : fx = x @ Wfx + bfx            [65536x512] -> bf16 (internal)
//   gemm : logits = x @ Wxs + bxs        [65536x256] -> f32 ([n][h*32+g])
//   k3   : softmax over g (scaled 1/temp[h]) in-place -> slice_weights (f32)
//   k4   : token[b,h,g,d] = sum_n fx*w ; norm[b,h,g] = sum_n w
//   k5   : tiny attention over G tokens per (b,h) -> out_slice (f32)
//   k6a  : out_x[n][h*64+d] = sum_g w * out_slice   -> bf16 (internal)
//   gemm : out = out_x @ Wout + bout -> d_out f32
// Workspace: ~193 MB.

typedef unsigned short u16;
typedef __attribute__((ext_vector_type(8))) unsigned short ushort8v;
typedef __attribute__((ext_vector_type(4))) unsigned short ushort4v;
typedef __attribute__((ext_vector_type(4))) float f32x4;

constexpr int Bc = 4, Nc = 16384, Hc = 8, Dc = 64, Gc = 32;
constexpr int BNc = Bc * Nc;          // 65536
constexpr int DIMc = 256, INNERc = 512;

__device__ inline float b2f(u16 v) {
    union { unsigned int u; float f; } t; t.u = ((unsigned int)v) << 16; return t.f;
}
__device__ inline u16 f2b(float f) {   // round-to-nearest-even
    union { float f; unsigned int u; } t; t.f = f;
    unsigned int u = t.u;
    return (u16)((u + 0x7fffu + ((u >> 16) & 1u)) >> 16);
}

// ---------------- k0: weight prep (all f32) ----------------
__global__ __launch_bounds__(256) void k0_fold(
    const float* __restrict__ Wx, const float* __restrict__ Wslice,
    const float* __restrict__ bx, const float* __restrict__ bslice,
    float* __restrict__ Wxs, float* __restrict__ bxs)
{
    int blk = blockIdx.x, tid = threadIdx.x;
    int h = tid >> 5, g = tid & 31;
    if (blk < 256) {
        int k = blk;
        float acc = 0.f;
        for (int d = 0; d < 64; d++)
            acc += Wx[k * INNERc + h * 64 + d] * Wslice[d * 32 + g];
        Wxs[k * 256 + tid] = acc;
    } else {
        float acc = 0.f;
        for (int d = 0; d < 64; d++)
            acc += bx[h * 64 + d] * Wslice[d * 32 + g];
        bxs[tid] = acc + bslice[g];
    }
}

// ------- tiled GEMM: C = A @ B + bias.  A: f32 or internal-bf16. B,bias: f32.
// 64x64 tile per 256-thread block, 4x4 per thread, BK=32, fp32 accumulate.
template <bool A_BF16, bool OUT_BF16>
__global__ __launch_bounds__(256) void k_gemm(
    const void* __restrict__ Ap, const float* __restrict__ Bm,
    const float* __restrict__ biasF, void* __restrict__ Cp,
    int Md, int Nd, int Kd)
{
    __shared__ float As[32][68];   // transposed: As[k][row]
    __shared__ float Bs[32][64];
    int tid = threadIdx.x;
    int tx = tid & 15, ty = tid >> 4;
    int row0 = blockIdx.y * 64, col0 = blockIdx.x * 64;
    float acc[4][4] = {};

    for (int k0 = 0; k0 < Kd; k0 += 32) {
        {   // stage A tile 64x32 (transposed into LDS); 8 elems/thread
            int r = tid >> 2, kq = (tid & 3) * 8;
            if (A_BF16) {
                const u16* A = (const u16*)Ap;
                ushort8v v = *(const ushort8v*)(A + (size_t)(row0 + r) * Kd + k0 + kq);
#pragma unroll
                for (int j = 0; j < 8; j++) As[kq + j][r] = b2f(v[j]);
            } else {
                const float* A = (const float*)Ap;
                const f32x4* src = (const f32x4*)(A + (size_t)(row0 + r) * Kd + k0 + kq);
                f32x4 v0 = src[0], v1 = src[1];
#pragma unroll
                for (int j = 0; j < 4; j++) { As[kq + j][r] = v0[j]; As[kq + 4 + j][r] = v1[j]; }
            }
        }
        {   // stage B tile 32x64 (f32)
            int kr = tid >> 3, c8 = (tid & 7) * 8;
            const f32x4* src = (const f32x4*)(Bm + (size_t)(k0 + kr) * Nd + col0 + c8);
            *(f32x4*)&Bs[kr][c8] = src[0];
            *(f32x4*)&Bs[kr][c8 + 4] = src[1];
        }
        __syncthreads();
#pragma unroll
        for (int k = 0; k < 32; k++) {
            f32x4 a = *(const f32x4*)&As[k][ty * 4];
            f32x4 b = *(const f32x4*)&Bs[k][tx * 4];
#pragma unroll
            for (int i = 0; i < 4; i++)
#pragma unroll
                for (int j = 0; j < 4; j++)
                    acc[i][j] += a[i] * b[j];
        }
        __syncthreads();
    }

#pragma unroll
    for (int i = 0; i < 4; i++) {
        int r = row0 + ty * 4 + i;
        int c = col0 + tx * 4;
        if (OUT_BF16) {
            u16* C = (u16*)Cp;
            ushort4v o;
#pragma unroll
            for (int j = 0; j < 4; j++) o[j] = f2b(acc[i][j] + biasF[c + j]);
            *(ushort4v*)(C + (size_t)r * Nd + c) = o;
        } else {
            float* C = (float*)Cp;
            f32x4 o;
#pragma unroll
            for (int j = 0; j < 4; j++) o[j] = acc[i][j] + biasF[c + j];
            *(f32x4*)(C + (size_t)r * Nd + c) = o;
        }
    }
}

// ---------------- k3: scaled softmax over g, in place ----------------
__global__ __launch_bounds__(256) void k3_softmax(float* __restrict__ sw,
                                                  const float* __restrict__ temp)
{
    int idx = blockIdx.x * 256 + threadIdx.x;   // point*8 + h
    int h = idx & 7;
    float* p = sw + (size_t)(idx >> 3) * 256 + h * 32;
    float inv = 1.0f / temp[h];
    float v[32];
    f32x4* pv = (f32x4*)p;
#pragma unroll
    for (int q = 0; q < 8; q++) {
        f32x4 t = pv[q];
#pragma unroll
        for (int j = 0; j < 4; j++) v[q * 4 + j] = t[j] * inv;
    }
    float m = -1e30f;
#pragma unroll
    for (int i = 0; i < 32; i++) m = fmaxf(m, v[i]);
    float s = 0.f;
#pragma unroll
    for (int i = 0; i < 32; i++) { v[i] = __expf(v[i] - m); s += v[i]; }
    float r = 1.0f / s;
#pragma unroll
    for (int q = 0; q < 8; q++) {
        f32x4 o;
#pragma unroll
        for (int j = 0; j < 4; j++) o[j] = v[q * 4 + j] * r;
        pv[q] = o;
    }
}

// ---------------- k4: token pooling + norm ----------------
__global__ __launch_bounds__(256) void k4_token(
    const float* __restrict__ sw, const u16* __restrict__ fx,
    float* __restrict__ token, float* __restrict__ norm)
{
    int bh = blockIdx.x;        // 0..31
    int chunk = blockIdx.y;     // 0..7
    int b = bh >> 3, h = bh & 7;
    int tid = threadIdx.x;
    int g = tid & 31, dq = tid >> 5;   // dq 0..7 -> d0 = dq*8
    __shared__ float wl[64][32];
    __shared__ float fxl[64][64];
    float accT[8] = {};
    float accN = 0.f;
    size_t nbase = (size_t)b * Nc + (size_t)chunk * 2048;

    for (int nn = 0; nn < 2048; nn += 64) {
        {
            int r = tid >> 2, c8 = (tid & 3) * 8;
            const f32x4* src = (const f32x4*)(sw + (nbase + nn + r) * 256 + h * 32 + c8);
            *(f32x4*)&wl[r][c8] = src[0];
            *(f32x4*)&wl[r][c8 + 4] = src[1];
        }
        {
            int r = tid >> 2, c16 = (tid & 3) * 16;
            const ushort8v* src = (const ushort8v*)(fx + (nbase + nn + r) * 512 + h * 64 + c16);
            ushort8v v0 = src[0], v1 = src[1];
#pragma unroll
            for (int j = 0; j < 8; j++) {
                fxl[r][c16 + j] = b2f(v0[j]);
                fxl[r][c16 + 8 + j] = b2f(v1[j]);
            }
        }
        __syncthreads();
        int d0 = dq * 8;
        for (int n = 0; n < 64; n++) {
            float wv = wl[n][g];
            if (dq == 0) accN += wv;
            f32x4 f0 = *(const f32x4*)&fxl[n][d0];
            f32x4 f1 = *(const f32x4*)&fxl[n][d0 + 4];
#pragma unroll
            for (int j = 0; j < 4; j++) {
                accT[j]     += wv * f0[j];
                accT[4 + j] += wv * f1[j];
            }
        }
        __syncthreads();
    }
    float* tptr = token + ((size_t)bh * 32 + g) * 64 + dq * 8;
#pragma unroll
    for (int j = 0; j < 8; j++) atomicAdd(tptr + j, accT[j]);
    if (dq == 0) atomicAdd(norm + bh * 32 + g, accN);
}

// ---------------- k5: tiny attention over G tokens ----------------
__global__ __launch_bounds__(256) void k5_attn(
    const float* __restrict__ token, const float* __restrict__ norm,
    const float* __restrict__ Wq, const float* __restrict__ Wk, const float* __restrict__ Wv,
    float* __restrict__ out_slice)
{
    __shared__ float tl[32][64];
    __shared__ float ql[32][64], kl[32][64], vl[32][64];
    __shared__ float sl[32][33];
    int bh = blockIdx.x, tid = threadIdx.x;
    const float* tk = token + (size_t)bh * 2048;

#pragma unroll
    for (int j = 0; j < 8; j++) {
        int idx = j * 256 + tid;
        int g = idx >> 6, d = idx & 63;
        tl[g][d] = tk[idx] / (norm[bh * 32 + g] + 1e-5f);
    }
    __syncthreads();
#pragma unroll
    for (int j = 0; j < 8; j++) {
        int idx = j * 256 + tid;
        int g = idx >> 6, d = idx & 63;
        float aq = 0.f, ak = 0.f, av = 0.f;
        for (int e = 0; e < 64; e++) {
            float t = tl[g][e];
            aq += t * Wq[e * 64 + d];
            ak += t * Wk[e * 64 + d];
            av += t * Wv[e * 64 + d];
        }
        ql[g][d] = aq; kl[g][d] = ak; vl[g][d] = av;
    }
    __syncthreads();
#pragma unroll
    for (int j = 0; j < 4; j++) {
        int idx = j * 256 + tid;
        int gq = idx >> 5, gk = idx & 31;
        float s = 0.f;
        for (int d = 0; d < 64; d++) s += ql[gq][d] * kl[gk][d];
        sl[gq][gk] = s * 0.125f;   // 1/sqrt(64)
    }
    __syncthreads();
    if (tid < 32) {
        float m = -1e30f;
        for (int k2 = 0; k2 < 32; k2++) m = fmaxf(m, sl[tid][k2]);
        float s = 0.f;
        for (int k2 = 0; k2 < 32; k2++) { float e = __expf(sl[tid][k2] - m); sl[tid][k2] = e; s += e; }
        float r = 1.0f / s;
        for (int k2 = 0; k2 < 32; k2++) sl[tid][k2] *= r;
    }
    __syncthreads();
#pragma unroll
    for (int j = 0; j < 8; j++) {
        int idx = j * 256 + tid;
        int g = idx >> 6, d = idx & 63;
        float a = 0.f;
        for (int k2 = 0; k2 < 32; k2++) a += sl[g][k2] * vl[k2][d];
        out_slice[(size_t)bh * 2048 + idx] = a;
    }
}

// ---------------- k6a: scatter out_slice back to points ----------------
__global__ __launch_bounds__(256) void k6a_scatter(
    const float* __restrict__ sw, const float* __restrict__ out_slice,
    u16* __restrict__ out_x)
{
    int t = blockIdx.x * 256 + threadIdx.x;   // point*8 + h
    int n = t >> 3, h = t & 7;
    int b = n >> 14;                          // N = 16384
    const float* wrow = sw + (size_t)n * 256 + h * 32;
    const float* os = out_slice + (size_t)(b * 8 + h) * 2048;
    float acc[64] = {};
    for (int g = 0; g < 32; g++) {
        float wv = wrow[g];
        const f32x4* osr = (const f32x4*)(os + g * 64);
#pragma unroll
        for (int q = 0; q < 16; q++) {
            f32x4 o = osr[q];
#pragma unroll
            for (int j = 0; j < 4; j++) acc[q * 4 + j] += wv * o[j];
        }
    }
    u16* dst = out_x + (size_t)n * 512 + h * 64;
#pragma unroll
    for (int q = 0; q < 8; q++) {
        ushort8v o;
#pragma unroll
        for (int j = 0; j < 8; j++) o[j] = f2b(acc[q * 8 + j]);
        *(ushort8v*)(dst + q * 8) = o;
    }
}

// ---------------- launcher ----------------
extern "C" void kernel_launch(void* const* d_in, const int* in_sizes, int n_in,
                              void* d_out, int out_size, void* d_ws, size_t ws_size,
                              hipStream_t stream)
{
    const float* x      = (const float*)d_in[0];
    const float* Wfx    = (const float*)d_in[1];
    const float* bfx    = (const float*)d_in[2];
    const float* Wx     = (const float*)d_in[3];
    const float* bx     = (const float*)d_in[4];
    const float* Wslice = (const float*)d_in[5];
    const float* bslice = (const float*)d_in[6];
    const float* temp   = (const float*)d_in[7];
    const float* Wq     = (const float*)d_in[8];
    const float* Wk     = (const float*)d_in[9];
    const float* Wv     = (const float*)d_in[10];
    const float* Wout   = (const float*)d_in[11];
    const float* bout   = (const float*)d_in[12];

    char* ws = (char*)d_ws;
    size_t off = 0;
    auto alloc = [&](size_t bytes) {
        void* p = ws + off;
        off = (off + bytes + 255) & ~(size_t)255;
        return p;
    };
    u16*   fx     = (u16*)  alloc((size_t)BNc * 512 * 2);   // 64 MiB (internal bf16)
    float* sw     = (float*)alloc((size_t)BNc * 256 * 4);   // 64 MiB
    u16*   out_x  = (u16*)  alloc((size_t)BNc * 512 * 2);   // 64 MiB (internal bf16)
    float* token  = (float*)alloc(65536 * 4);               // 256 KB
    float* norm   = (float*)alloc(1024 * 4);                // contiguous after token
    float* oslice = (float*)alloc(65536 * 4);
    float* Wxs    = (float*)alloc(256 * 256 * 4);
    float* bxs    = (float*)alloc(256 * 4);

    // zero token + norm accumulators (contiguous block)
    hipMemsetAsync(token, 0, 65536 * 4 + 1024 * 4, stream);

    k0_fold<<<257, 256, 0, stream>>>(Wx, Wslice, bx, bslice, Wxs, bxs);

    // fx = x @ Wfx + bfx  -> bf16 [65536 x 512]
    k_gemm<false, true><<<dim3(512 / 64, BNc / 64), 256, 0, stream>>>(
        x, Wfx, bfx, fx, BNc, 512, 256);

    // logits = x @ Wxs + bxs -> f32 [65536 x 256]
    k_gemm<false, false><<<dim3(256 / 64, BNc / 64), 256, 0, stream>>>(
        x, Wxs, bxs, sw, BNc, 256, 256);

    k3_softmax<<<BNc * 8 / 256, 256, 0, stream>>>(sw, temp);

    k4_token<<<dim3(32, 8), 256, 0, stream>>>(sw, fx, token, norm);

    k5_attn<<<32, 256, 0, stream>>>(token, norm, Wq, Wk, Wv, oslice);

    k6a_scatter<<<BNc * 8 / 256, 256, 0, stream>>>(sw, oslice, out_x);

    // out = out_x @ Wout + bout -> f32 d_out
    k_gemm<true, false><<<dim3(256 / 64, BNc / 64), 256, 0, stream>>>(
        out_x, Wout, bout, d_out, BNc, 256, 512);
}

// Round 3
// 591.711 us; speedup vs baseline: 2.2869x; 2.2869x over previous
//
#include <hip/hip_runtime.h>

// Physics_Attention_Irregular_Mesh — round 2
// B=4, N=16384, DIM=256, H=8, D=64, G=32, inner=512. f32 I/O.
// Changes vs r1: (1) k6a scatter restructured (no acc[64] scratch spill),
// (2) the three GEMMs use bf16 MFMA 16x16x32 (Wout hi/lo-compensated),
// (3) k4_token 4x more blocks. out_x aliases fx buffer (ws ~161 MiB).

typedef unsigned short u16;
typedef __attribute__((ext_vector_type(8))) unsigned short ushort8v;
typedef __attribute__((ext_vector_type(4))) unsigned short ushort4v;
typedef __attribute__((ext_vector_type(8))) short short8v;
typedef __attribute__((ext_vector_type(4))) float f32x4;

constexpr int Nc = 16384;
constexpr int BNc = 4 * Nc;           // 65536
constexpr int INNERc = 512;

__device__ inline float b2f(u16 v) {
    union { unsigned int u; float f; } t; t.u = ((unsigned int)v) << 16; return t.f;
}
__device__ inline u16 f2b(float f) {   // round-to-nearest-even
    union { float f; unsigned int u; } t; t.f = f;
    unsigned int u = t.u;
    return (u16)((u + 0x7fffu + ((u >> 16) & 1u)) >> 16);
}

// ---------------- prep: x (f32) -> bf16 ----------------
__global__ __launch_bounds__(256) void kconv_x(const float* __restrict__ x,
                                               u16* __restrict__ xb)
{
    int t = blockIdx.x * 256 + threadIdx.x;
    f32x4 v = ((const f32x4*)x)[t];
    ushort4v o;
#pragma unroll
    for (int j = 0; j < 4; j++) o[j] = f2b(v[j]);
    ((ushort4v*)xb)[t] = o;
}

// ---------------- prep: fold WxsT[g+h*32][k] = (Wx_h @ Wslice)^T, bxs ------
__global__ __launch_bounds__(256) void k0_fold(
    const float* __restrict__ Wx, const float* __restrict__ Wslice,
    const float* __restrict__ bx, const float* __restrict__ bslice,
    u16* __restrict__ WxsT, float* __restrict__ bxs)
{
    int blk = blockIdx.x, tid = threadIdx.x;
    int h = tid >> 5, g = tid & 31;
    if (blk < 256) {
        int k = blk;
        float acc = 0.f;
        for (int d = 0; d < 64; d++)
            acc += Wx[k * INNERc + h * 64 + d] * Wslice[d * 32 + g];
        WxsT[tid * 256 + k] = f2b(acc);   // transposed: [n=h*32+g][k]
    } else {
        float acc = 0.f;
        for (int d = 0; d < 64; d++)
            acc += bx[h * 64 + d] * Wslice[d * 32 + g];
        bxs[tid] = acc + bslice[g];
    }
}

// ---------------- prep: WfxT[n][k] bf16 ----------------
__global__ __launch_bounds__(256) void kprep_wfx(const float* __restrict__ Wfx,
                                                 u16* __restrict__ WfxT)
{
    int n = blockIdx.x, k = threadIdx.x;        // 512 blocks x 256
    WfxT[n * 256 + k] = f2b(Wfx[k * 512 + n]);
}

// ---------------- prep: WoutT hi/lo [n][k] bf16 ----------------
__global__ __launch_bounds__(256) void kprep_wout(const float* __restrict__ Wout,
                                                  u16* __restrict__ WoutT_hi,
                                                  u16* __restrict__ WoutT_lo)
{
    int n = blockIdx.x;                         // 256 blocks x 256
#pragma unroll
    for (int q = 0; q < 2; q++) {
        int kk = threadIdx.x + q * 256;
        float w = Wout[(size_t)kk * 256 + n];
        u16 hi = f2b(w);
        WoutT_hi[n * 512 + kk] = hi;
        WoutT_lo[n * 512 + kk] = f2b(w - b2f(hi));
    }
}

// ------- MFMA GEMM: C[M][Nd] = A[M][K] @ Bt[Nd][K]^T + bias ------------
// A, Bt bf16 row-major. Block 256 thr = 4 waves; tile 64(M) x 64(N), BK=32.
// Wave w owns m-strip [w*16, w*16+16); 4 MFMA n-tiles of 16.
// Frag layouts (m89/m91/m120-verified): A[m=lane&15][k=quad*8+j],
// B[k=quad*8+j][n=lane&15] (from Bt rows), D[row=quad*4+r][col=lane&15].
template <bool OUT_BF16, bool COMP>
__global__ __launch_bounds__(256) void k_mfma_gemm(
    const u16* __restrict__ A, const u16* __restrict__ Bt,
    const u16* __restrict__ BtLo, const float* __restrict__ biasF,
    void* __restrict__ Cp, int Nd, int Kd)
{
    __shared__ u16 Asl[4][64][8];    // [k-quad][m][j]
    __shared__ u16 Bsl[4][64][8];    // [k-quad][n][j]
    __shared__ u16 Bsl2[4][64][8];
    int tid = threadIdx.x;
    int wave = tid >> 6, lane = tid & 63;
    int lm = lane & 15, quad = lane >> 4;
    int row0 = blockIdx.y * 64, col0 = blockIdx.x * 64;
    int sm = tid >> 2, skb = tid & 3;        // staging: row sm, k-chunk skb
    f32x4 acc[4] = {};

    for (int k0 = 0; k0 < Kd; k0 += 32) {
        *(ushort8v*)&Asl[skb][sm][0] =
            *(const ushort8v*)(A + (size_t)(row0 + sm) * Kd + k0 + skb * 8);
        *(ushort8v*)&Bsl[skb][sm][0] =
            *(const ushort8v*)(Bt + (size_t)(col0 + sm) * Kd + k0 + skb * 8);
        if (COMP)
            *(ushort8v*)&Bsl2[skb][sm][0] =
                *(const ushort8v*)(BtLo + (size_t)(col0 + sm) * Kd + k0 + skb * 8);
        __syncthreads();
        short8v af = *(short8v*)&Asl[quad][wave * 16 + lm][0];
#pragma unroll
        for (int nt = 0; nt < 4; nt++) {
            short8v bh = *(short8v*)&Bsl[quad][nt * 16 + lm][0];
            acc[nt] = __builtin_amdgcn_mfma_f32_16x16x32_bf16(af, bh, acc[nt], 0, 0, 0);
            if (COMP) {
                short8v bl = *(short8v*)&Bsl2[quad][nt * 16 + lm][0];
                acc[nt] = __builtin_amdgcn_mfma_f32_16x16x32_bf16(af, bl, acc[nt], 0, 0, 0);
            }
        }
        __syncthreads();
    }

#pragma unroll
    for (int nt = 0; nt < 4; nt++) {
        int col = col0 + nt * 16 + lm;
        float bv = biasF[col];
#pragma unroll
        for (int r = 0; r < 3 + 1; r++) {
            int row = row0 + wave * 16 + quad * 4 + r;
            float v = acc[nt][r] + bv;
            if (OUT_BF16) ((u16*)Cp)[(size_t)row * Nd + col] = f2b(v);
            else          ((float*)Cp)[(size_t)row * Nd + col] = v;
        }
    }
}

// ---------------- k3: scaled softmax over g, in place ----------------
__global__ __launch_bounds__(256) void k3_softmax(float* __restrict__ sw,
                                                  const float* __restrict__ temp)
{
    int idx = blockIdx.x * 256 + threadIdx.x;   // point*8 + h
    int h = idx & 7;
    float* p = sw + (size_t)(idx >> 3) * 256 + h * 32;
    float inv = 1.0f / temp[h];
    float v[32];
    f32x4* pv = (f32x4*)p;
#pragma unroll
    for (int q = 0; q < 8; q++) {
        f32x4 t = pv[q];
#pragma unroll
        for (int j = 0; j < 4; j++) v[q * 4 + j] = t[j] * inv;
    }
    float m = -1e30f;
#pragma unroll
    for (int i = 0; i < 32; i++) m = fmaxf(m, v[i]);
    float s = 0.f;
#pragma unroll
    for (int i = 0; i < 32; i++) { v[i] = __expf(v[i] - m); s += v[i]; }
    float r = 1.0f / s;
#pragma unroll
    for (int q = 0; q < 8; q++) {
        f32x4 o;
#pragma unroll
        for (int j = 0; j < 4; j++) o[j] = v[q * 4 + j] * r;
        pv[q] = o;
    }
}

// ---------------- k4: token pooling + norm ----------------
__global__ __launch_bounds__(256) void k4_token(
    const float* __restrict__ sw, const u16* __restrict__ fx,
    float* __restrict__ token, float* __restrict__ norm)
{
    int bh = blockIdx.x;        // 0..31
    int chunk = blockIdx.y;     // 0..31 (512-point chunks)
    int b = bh >> 3, h = bh & 7;
    int tid = threadIdx.x;
    int g = tid & 31, dq = tid >> 5;   // dq 0..7 -> d0 = dq*8
    __shared__ float wl[64][32];
    __shared__ float fxl[64][64];
    float accT[8] = {};
    float accN = 0.f;
    size_t nbase = (size_t)b * Nc + (size_t)chunk * 512;

    for (int nn = 0; nn < 512; nn += 64) {
        {
            int r = tid >> 2, c8 = (tid & 3) * 8;
            const f32x4* src = (const f32x4*)(sw + (nbase + nn + r) * 256 + h * 32 + c8);
            *(f32x4*)&wl[r][c8] = src[0];
            *(f32x4*)&wl[r][c8 + 4] = src[1];
        }
        {
            int r = tid >> 2, c16 = (tid & 3) * 16;
            const ushort8v* src = (const ushort8v*)(fx + (nbase + nn + r) * 512 + h * 64 + c16);
            ushort8v v0 = src[0], v1 = src[1];
#pragma unroll
            for (int j = 0; j < 8; j++) {
                fxl[r][c16 + j] = b2f(v0[j]);
                fxl[r][c16 + 8 + j] = b2f(v1[j]);
            }
        }
        __syncthreads();
        int d0 = dq * 8;
        for (int n = 0; n < 64; n++) {
            float wv = wl[n][g];
            if (dq == 0) accN += wv;
            f32x4 f0 = *(const f32x4*)&fxl[n][d0];
            f32x4 f1 = *(const f32x4*)&fxl[n][d0 + 4];
#pragma unroll
            for (int j = 0; j < 4; j++) {
                accT[j]     += wv * f0[j];
                accT[4 + j] += wv * f1[j];
            }
        }
        __syncthreads();
    }
    float* tptr = token + ((size_t)bh * 32 + g) * 64 + dq * 8;
#pragma unroll
    for (int j = 0; j < 8; j++) atomicAdd(tptr + j, accT[j]);
    if (dq == 0) atomicAdd(norm + bh * 32 + g, accN);
}

// ---------------- k5: tiny attention over G tokens ----------------
__global__ __launch_bounds__(256) void k5_attn(
    const float* __restrict__ token, const float* __restrict__ norm,
    const float* __restrict__ Wq, const float* __restrict__ Wk, const float* __restrict__ Wv,
    float* __restrict__ out_slice)
{
    __shared__ float tl[32][64];
    __shared__ float ql[32][64], kl[32][64], vl[32][64];
    __shared__ float sl[32][33];
    int bh = blockIdx.x, tid = threadIdx.x;
    const float* tk = token + (size_t)bh * 2048;

#pragma unroll
    for (int j = 0; j < 8; j++) {
        int idx = j * 256 + tid;
        int g = idx >> 6, d = idx & 63;
        tl[g][d] = tk[idx] / (norm[bh * 32 + g] + 1e-5f);
    }
    __syncthreads();
#pragma unroll
    for (int j = 0; j < 8; j++) {
        int idx = j * 256 + tid;
        int g = idx >> 6, d = idx & 63;
        float aq = 0.f, ak = 0.f, av = 0.f;
        for (int e = 0; e < 64; e++) {
            float t = tl[g][e];
            aq += t * Wq[e * 64 + d];
            ak += t * Wk[e * 64 + d];
            av += t * Wv[e * 64 + d];
        }
        ql[g][d] = aq; kl[g][d] = ak; vl[g][d] = av;
    }
    __syncthreads();
#pragma unroll
    for (int j = 0; j < 4; j++) {
        int idx = j * 256 + tid;
        int gq = idx >> 5, gk = idx & 31;
        float s = 0.f;
        for (int d = 0; d < 64; d++) s += ql[gq][d] * kl[gk][d];
        sl[gq][gk] = s * 0.125f;   // 1/sqrt(64)
    }
    __syncthreads();
    if (tid < 32) {
        float m = -1e30f;
        for (int k2 = 0; k2 < 32; k2++) m = fmaxf(m, sl[tid][k2]);
        float s = 0.f;
        for (int k2 = 0; k2 < 32; k2++) { float e = __expf(sl[tid][k2] - m); sl[tid][k2] = e; s += e; }
        float r = 1.0f / s;
        for (int k2 = 0; k2 < 32; k2++) sl[tid][k2] *= r;
    }
    __syncthreads();
#pragma unroll
    for (int j = 0; j < 8; j++) {
        int idx = j * 256 + tid;
        int g = idx >> 6, d = idx & 63;
        float a = 0.f;
        for (int k2 = 0; k2 < 32; k2++) a += sl[g][k2] * vl[k2][d];
        out_slice[(size_t)bh * 2048 + idx] = a;
    }
}

// ---------------- k6a: scatter out_slice back to points ----------------
// thread = (n, h, dq): 8 outputs each -> acc stays in registers.
__global__ __launch_bounds__(256) void k6a_scatter(
    const float* __restrict__ sw, const float* __restrict__ out_slice,
    u16* __restrict__ out_x)
{
    int t = blockIdx.x * 256 + threadIdx.x;   // (n*8 + h)*8 + dq
    int dq = t & 7, h = (t >> 3) & 7, n = t >> 6;
    int b = n >> 14;                          // N = 16384
    const float* wrow = sw + (size_t)n * 256 + h * 32;
    const float* os = out_slice + (size_t)(b * 8 + h) * 2048 + dq * 8;
    float acc[8] = {};
    for (int g = 0; g < 32; g++) {
        float wv = wrow[g];
        f32x4 o0 = *(const f32x4*)(os + g * 64);
        f32x4 o1 = *(const f32x4*)(os + g * 64 + 4);
#pragma unroll
        for (int j = 0; j < 4; j++) {
            acc[j]     += wv * o0[j];
            acc[4 + j] += wv * o1[j];
        }
    }
    ushort8v o;
#pragma unroll
    for (int j = 0; j < 8; j++) o[j] = f2b(acc[j]);
    *(ushort8v*)(out_x + (size_t)n * 512 + h * 64 + dq * 8) = o;
}

// ---------------- launcher ----------------
extern "C" void kernel_launch(void* const* d_in, const int* in_sizes, int n_in,
                              void* d_out, int out_size, void* d_ws, size_t ws_size,
                              hipStream_t stream)
{
    const float* x      = (const float*)d_in[0];
    const float* Wfx    = (const float*)d_in[1];
    const float* bfx    = (const float*)d_in[2];
    const float* Wx     = (const float*)d_in[3];
    const float* bx     = (const float*)d_in[4];
    const float* Wslice = (const float*)d_in[5];
    const float* bslice = (const float*)d_in[6];
    const float* temp   = (const float*)d_in[7];
    const float* Wq     = (const float*)d_in[8];
    const float* Wk     = (const float*)d_in[9];
    const float* Wv     = (const float*)d_in[10];
    const float* Wout   = (const float*)d_in[11];
    const float* bout   = (const float*)d_in[12];

    char* ws = (char*)d_ws;
    size_t off = 0;
    auto alloc = [&](size_t bytes) {
        void* p = ws + off;
        off = (off + bytes + 255) & ~(size_t)255;
        return p;
    };
    u16*   fx     = (u16*)  alloc((size_t)BNc * 512 * 2);   // 64 MiB (bf16); reused as out_x
    float* sw     = (float*)alloc((size_t)BNc * 256 * 4);   // 64 MiB
    u16*   xb     = (u16*)  alloc((size_t)BNc * 256 * 2);   // 32 MiB (x as bf16)
    float* token  = (float*)alloc(65536 * 4);               // 256 KB
    float* norm   = (float*)alloc(1024 * 4);                // contiguous after token
    float* oslice = (float*)alloc(65536 * 4);
    u16*   WfxT   = (u16*)  alloc(512 * 256 * 2);
    u16*   WxsT   = (u16*)  alloc(256 * 256 * 2);
    u16*   WoutTh = (u16*)  alloc(256 * 512 * 2);
    u16*   WoutTl = (u16*)  alloc(256 * 512 * 2);
    float* bxs    = (float*)alloc(256 * 4);
    u16*   out_x  = fx;   // fx dead after k4_token; safe alias

    hipMemsetAsync(token, 0, 65536 * 4 + 1024 * 4, stream);

    kconv_x<<<BNc * 256 / 4 / 256, 256, 0, stream>>>(x, xb);
    k0_fold<<<257, 256, 0, stream>>>(Wx, Wslice, bx, bslice, WxsT, bxs);
    kprep_wfx<<<512, 256, 0, stream>>>(Wfx, WfxT);
    kprep_wout<<<256, 256, 0, stream>>>(Wout, WoutTh, WoutTl);

    // fx = x @ Wfx + bfx -> bf16 [65536 x 512]
    k_mfma_gemm<true, false><<<dim3(512 / 64, BNc / 64), 256, 0, stream>>>(
        xb, WfxT, nullptr, bfx, fx, 512, 256);

    // logits = x @ Wxs + bxs -> f32 [65536 x 256]
    k_mfma_gemm<false, false><<<dim3(256 / 64, BNc / 64), 256, 0, stream>>>(
        xb, WxsT, nullptr, bxs, sw, 256, 256);

    k3_softmax<<<BNc * 8 / 256, 256, 0, stream>>>(sw, temp);

    k4_token<<<dim3(32, 32), 256, 0, stream>>>(sw, fx, token, norm);

    k5_attn<<<32, 256, 0, stream>>>(token, norm, Wq, Wk, Wv, oslice);

    k6a_scatter<<<BNc * 64 / 256, 256, 0, stream>>>(sw, oslice, out_x);

    // out = out_x @ Wout + bout -> f32 d_out  (hi/lo-compensated Wout)
    k_mfma_gemm<false, true><<<dim3(256 / 64, BNc / 64), 256, 0, stream>>>(
        out_x, WoutTh, WoutTl, bout, d_out, 256, 512);
}

// Round 4
// 400.164 us; speedup vs baseline: 3.3816x; 1.4787x over previous
//
#include <hip/hip_runtime.h>

// Physics_Attention_Irregular_Mesh — round 3
// B=4, N=16384, DIM=256, H=8, D=64, G=32, inner=512. f32 I/O.
// Structure:
//   k0_fold   : WxsT[hg][256] = (Wx_h @ Wslice)^T bf16, bxs f32
//   kprep_wfx : WfxT[512][256] bf16
//   kgemm<0>  : fxT[c][n] bf16 = (x @ Wfx + bfx)^T       (transposed epilogue)
//   kgemm<1>  : logits GEMM + fused softmax -> swb[n][256] + swT[bh*32+g][n] bf16
//   k4        : token_part = swT @ fx (MFMA, split-K, direct-global frags) + norm_part
//   k4b       : tl[bh][g][d] = token/(norm+1e-5)
//   k5        : tiny attention over G tokens -> oslice f32
//   kZ        : ZT[b][c][hg] bf16 = (os_bh @ Wout_h)^T
//   kgemm<2>  : out = swb @ ZT_b^T + bout -> d_out f32
// out_x / k6a eliminated algebraically: out = sw @ (os @ Wout).

typedef unsigned short u16;
typedef __attribute__((ext_vector_type(8))) unsigned short ushort8v;
typedef __attribute__((ext_vector_type(4))) unsigned short ushort4v;
typedef __attribute__((ext_vector_type(8))) short short8v;
typedef __attribute__((ext_vector_type(4))) float f32x4;

constexpr int Nc = 16384;
constexpr int BNc = 65536;

__device__ inline float b2f(u16 v) {
    union { unsigned int u; float f; } t; t.u = ((unsigned int)v) << 16; return t.f;
}
__device__ inline u16 f2b(float f) {   // round-to-nearest-even
    union { float f; unsigned int u; } t; t.f = f;
    unsigned int u = t.u;
    return (u16)((u + 0x7fffu + ((u >> 16) & 1u)) >> 16);
}

// ---------------- prep: fold WxsT[h*32+g][k] = (Wx_h @ Wslice)^T, bxs ------
__global__ __launch_bounds__(256) void k0_fold(
    const float* __restrict__ Wx, const float* __restrict__ Wslice,
    const float* __restrict__ bx, const float* __restrict__ bslice,
    u16* __restrict__ WxsT, float* __restrict__ bxs)
{
    int blk = blockIdx.x, tid = threadIdx.x;
    int h = tid >> 5, g = tid & 31;
    if (blk < 256) {
        int k = blk;
        float acc = 0.f;
        for (int d = 0; d < 64; d++)
            acc += Wx[k * 512 + h * 64 + d] * Wslice[d * 32 + g];
        WxsT[tid * 256 + k] = f2b(acc);
    } else {
        float acc = 0.f;
        for (int d = 0; d < 64; d++)
            acc += bx[h * 64 + d] * Wslice[d * 32 + g];
        bxs[tid] = acc + bslice[g];
    }
}

// ---------------- prep: WfxT[n][k] bf16 ----------------
__global__ __launch_bounds__(256) void kprep_wfx(const float* __restrict__ Wfx,
                                                 u16* __restrict__ WfxT)
{
    int n = blockIdx.x, k = threadIdx.x;        // 512 blocks x 256
    WfxT[n * 256 + k] = f2b(Wfx[k * 512 + n]);
}

// ------- MFMA GEMM, 64x64 tile, BK=32, 4 waves, 16x16x32 bf16. -------------
// MODE 0: A=f32 x, Bt=WfxT, out fxT[c][65536] bf16 (+bias)
// MODE 1: A=f32 x, Bt=WxsT, fused softmax epilogue -> swb[n][256], swT[...][16384]
// MODE 2: A=bf16 swb, Bt=ZT (per-batch, +b*65536), out f32 [n][256] (+bias)
template <int MODE>
__global__ __launch_bounds__(256) void kgemm(
    const void* __restrict__ Ap, const u16* __restrict__ Bt,
    const float* __restrict__ bias, const float* __restrict__ temp,
    void* __restrict__ O1, u16* __restrict__ O2, int Kd)
{
    __shared__ u16 Asl[4][64][8];    // [k-quad][m][j]
    __shared__ u16 Bsl[4][64][8];    // [k-quad][n][j]
    int tid = threadIdx.x;
    int wave = tid >> 6, lane = tid & 63;
    int lm = lane & 15, quad = lane >> 4;
    int row0 = blockIdx.y * 64, col0 = blockIdx.x * 64;
    int sm = tid >> 2, skb = tid & 3;
    const u16* BtB = Bt;
    if (MODE == 2) BtB += (size_t)(row0 >> 14) * 65536;
    f32x4 acc[4] = {};

    for (int k0 = 0; k0 < Kd; k0 += 32) {
        if (MODE < 2) {
            const float* A32 = (const float*)Ap;
            const f32x4* src = (const f32x4*)(A32 + (size_t)(row0 + sm) * Kd + k0 + skb * 8);
            f32x4 v0 = src[0], v1 = src[1];
            ushort8v o;
#pragma unroll
            for (int j = 0; j < 4; j++) { o[j] = f2b(v0[j]); o[4 + j] = f2b(v1[j]); }
            *(ushort8v*)&Asl[skb][sm][0] = o;
        } else {
            const u16* A16 = (const u16*)Ap;
            *(ushort8v*)&Asl[skb][sm][0] =
                *(const ushort8v*)(A16 + (size_t)(row0 + sm) * Kd + k0 + skb * 8);
        }
        *(ushort8v*)&Bsl[skb][sm][0] =
            *(const ushort8v*)(BtB + (size_t)(col0 + sm) * Kd + k0 + skb * 8);
        __syncthreads();
        short8v af = *(short8v*)&Asl[quad][wave * 16 + lm][0];
#pragma unroll
        for (int nt = 0; nt < 4; nt++) {
            short8v bf = *(short8v*)&Bsl[quad][nt * 16 + lm][0];
            acc[nt] = __builtin_amdgcn_mfma_f32_16x16x32_bf16(af, bf, acc[nt], 0, 0, 0);
        }
        __syncthreads();
    }

    if (MODE == 0) {
        u16* fxT = (u16*)O1;
        int nbase = row0 + wave * 16 + quad * 4;
#pragma unroll
        for (int nt = 0; nt < 4; nt++) {
            int c = col0 + nt * 16 + lm;
            float bv = bias[c];
            ushort4v o;
#pragma unroll
            for (int r = 0; r < 4; r++) o[r] = f2b(acc[nt][r] + bv);
            *(ushort4v*)(fxT + (size_t)c * 65536 + nbase) = o;
        }
    } else if (MODE == 1) {
        int b = row0 >> 14, h0 = col0 >> 5;     // 2 heads per 64-col tile
        int nlbase = (row0 & 16383) + wave * 16 + quad * 4;
        u16* swb = (u16*)O1;
        float it0 = 1.0f / temp[h0], it1 = 1.0f / temp[h0 + 1];
#pragma unroll
        for (int hh = 0; hh < 2; hh++) {
            float it = hh ? it1 : it0;
            float bv0 = bias[col0 + hh * 32 + lm];
            float bv1 = bias[col0 + hh * 32 + 16 + lm];
            ushort4v p0, p1;
#pragma unroll
            for (int r = 0; r < 4; r++) {
                float v0 = (acc[2 * hh][r] + bv0) * it;        // g = lm
                float v1 = (acc[2 * hh + 1][r] + bv1) * it;    // g = 16+lm
                float m = fmaxf(v0, v1);
                m = fmaxf(m, __shfl_xor(m, 1));
                m = fmaxf(m, __shfl_xor(m, 2));
                m = fmaxf(m, __shfl_xor(m, 4));
                m = fmaxf(m, __shfl_xor(m, 8));
                float e0 = __expf(v0 - m), e1 = __expf(v1 - m);
                float s = e0 + e1;
                s += __shfl_xor(s, 1);
                s += __shfl_xor(s, 2);
                s += __shfl_xor(s, 4);
                s += __shfl_xor(s, 8);
                float rs = 1.0f / s;
                float w0 = e0 * rs, w1 = e1 * rs;
                int row = row0 + wave * 16 + quad * 4 + r;
                swb[(size_t)row * 256 + col0 + hh * 32 + lm] = f2b(w0);
                swb[(size_t)row * 256 + col0 + hh * 32 + 16 + lm] = f2b(w1);
                p0[r] = f2b(w0); p1[r] = f2b(w1);
            }
            size_t gbase = (size_t)((b * 8 + h0 + hh) * 32);
            *(ushort4v*)(O2 + (gbase + lm) * 16384 + nlbase) = p0;
            *(ushort4v*)(O2 + (gbase + 16 + lm) * 16384 + nlbase) = p1;
        }
    } else {
        float* out = (float*)O1;
#pragma unroll
        for (int nt = 0; nt < 4; nt++) {
            int c = col0 + nt * 16 + lm;
            float bv = bias[c];
#pragma unroll
            for (int r = 0; r < 4; r++)
                out[(size_t)(row0 + wave * 16 + quad * 4 + r) * 256 + c] = acc[nt][r] + bv;
        }
    }
}

// ---------------- k4: token pooling via MFMA, split-K ----------------
// block (bh, ky): token_part[ky][bh][32][64] += swT_h[32 x 512] @ fx[512 x 64]
// wave w: m-tile mt=w&1 (g 0-15/16-31), d-pair dp=w>>1 (d-tiles 2dp,2dp+1).
__global__ __launch_bounds__(256) void k4_token_mfma(
    const u16* __restrict__ swT, const u16* __restrict__ fxT,
    float* __restrict__ token_part, float* __restrict__ norm_part)
{
    int bh = blockIdx.x, ky = blockIdx.y;
    int b = bh >> 3, h = bh & 7;
    int tid = threadIdx.x, wave = tid >> 6, lane = tid & 63;
    int lm = lane & 15, quad = lane >> 4;
    int mt = wave & 1, dp = wave >> 1;
    const u16* Ar = swT + ((size_t)(bh * 32 + mt * 16 + lm)) * 16384 + ky * 512 + quad * 8;
    const u16* Br0 = fxT + ((size_t)(h * 64 + dp * 32 + lm)) * 65536
                     + (size_t)b * 16384 + ky * 512 + quad * 8;
    const u16* Br1 = Br0 + (size_t)16 * 65536;
    f32x4 acc0 = {}, acc1 = {};
    float nacc = 0.f;
#pragma unroll
    for (int kk = 0; kk < 16; kk++) {
        short8v af = *(const short8v*)(Ar + kk * 32);
        short8v b0 = *(const short8v*)(Br0 + kk * 32);
        short8v b1 = *(const short8v*)(Br1 + kk * 32);
        acc0 = __builtin_amdgcn_mfma_f32_16x16x32_bf16(af, b0, acc0, 0, 0, 0);
        acc1 = __builtin_amdgcn_mfma_f32_16x16x32_bf16(af, b1, acc1, 0, 0, 0);
        if (dp == 0) {
            ushort8v au = (ushort8v&)af;
#pragma unroll
            for (int j = 0; j < 8; j++) nacc += b2f(au[j]);
        }
    }
    float* tp = token_part + ((size_t)(ky * 32 + bh)) * 2048;
#pragma unroll
    for (int r = 0; r < 4; r++) {
        int g = mt * 16 + quad * 4 + r;
        tp[g * 64 + dp * 32 + lm] = acc0[r];
        tp[g * 64 + dp * 32 + 16 + lm] = acc1[r];
    }
    if (dp == 0) {
        nacc += __shfl_xor(nacc, 16);
        nacc += __shfl_xor(nacc, 32);
        if (lane < 16)
            norm_part[(ky * 32 + bh) * 32 + mt * 16 + lm] = nacc;
    }
}

// ---------------- k4b: reduce partials -> tl = token/(norm+1e-5) ----------
__global__ __launch_bounds__(256) void k4b_reduce(
    const float* __restrict__ tp, const float* __restrict__ np,
    float* __restrict__ tl)
{
    int t = blockIdx.x * 256 + threadIdx.x;   // 65536
    int bh = t >> 11, e = t & 2047, g = e >> 6;
    float ts = 0.f, ns = 0.f;
    for (int ch = 0; ch < 32; ch++) {
        ts += tp[((size_t)(ch * 32 + bh)) * 2048 + e];
        ns += np[(ch * 32 + bh) * 32 + g];
    }
    tl[t] = ts / (ns + 1e-5f);
}

// ---------------- k5: tiny attention over G tokens ----------------
__global__ __launch_bounds__(256) void k5_attn(
    const float* __restrict__ tlg,
    const float* __restrict__ Wq, const float* __restrict__ Wk, const float* __restrict__ Wv,
    float* __restrict__ out_slice)
{
    __shared__ float tl[32][64];
    __shared__ float ql[32][64], kl[32][64], vl[32][64];
    __shared__ float sl[32][33];
    int bh = blockIdx.x, tid = threadIdx.x;
    const float* tk = tlg + (size_t)bh * 2048;

#pragma unroll
    for (int j = 0; j < 8; j++) {
        int idx = j * 256 + tid;
        tl[idx >> 6][idx & 63] = tk[idx];
    }
    __syncthreads();
#pragma unroll
    for (int j = 0; j < 8; j++) {
        int idx = j * 256 + tid;
        int g = idx >> 6, d = idx & 63;
        float aq = 0.f, ak = 0.f, av = 0.f;
        for (int e = 0; e < 64; e++) {
            float t = tl[g][e];
            aq += t * Wq[e * 64 + d];
            ak += t * Wk[e * 64 + d];
            av += t * Wv[e * 64 + d];
        }
        ql[g][d] = aq; kl[g][d] = ak; vl[g][d] = av;
    }
    __syncthreads();
#pragma unroll
    for (int j = 0; j < 4; j++) {
        int idx = j * 256 + tid;
        int gq = idx >> 5, gk = idx & 31;
        float s = 0.f;
        for (int d = 0; d < 64; d++) s += ql[gq][d] * kl[gk][d];
        sl[gq][gk] = s * 0.125f;   // 1/sqrt(64)
    }
    __syncthreads();
    if (tid < 32) {
        float m = -1e30f;
        for (int k2 = 0; k2 < 32; k2++) m = fmaxf(m, sl[tid][k2]);
        float s = 0.f;
        for (int k2 = 0; k2 < 32; k2++) { float e = __expf(sl[tid][k2] - m); sl[tid][k2] = e; s += e; }
        float r = 1.0f / s;
        for (int k2 = 0; k2 < 32; k2++) sl[tid][k2] *= r;
    }
    __syncthreads();
#pragma unroll
    for (int j = 0; j < 8; j++) {
        int idx = j * 256 + tid;
        int g = idx >> 6, d = idx & 63;
        float a = 0.f;
        for (int k2 = 0; k2 < 32; k2++) a += sl[g][k2] * vl[k2][d];
        out_slice[(size_t)bh * 2048 + idx] = a;
    }
}

// ---------------- kZ: ZT[b][c][hg] = (os_bh @ Wout_h)^T, bf16 -------------
__global__ __launch_bounds__(256) void kZ(
    const float* __restrict__ os, const float* __restrict__ Wout,
    u16* __restrict__ ZT)
{
    int b = blockIdx.x, cb = blockIdx.y;   // grid (4, 16)
    int t = threadIdx.x;
    int c = cb * 16 + (t & 15), kq = t >> 4;
    for (int k = kq * 16; k < kq * 16 + 16; k++) {
        int h = k >> 5, g = k & 31;
        const float* osr = os + ((size_t)(b * 8 + h)) * 2048 + g * 64;
        float acc = 0.f;
        for (int d = 0; d < 64; d++)
            acc += osr[d] * Wout[(h * 64 + d) * 256 + c];
        ZT[(size_t)b * 65536 + c * 256 + k] = f2b(acc);
    }
}

// ---------------- launcher ----------------
extern "C" void kernel_launch(void* const* d_in, const int* in_sizes, int n_in,
                              void* d_out, int out_size, void* d_ws, size_t ws_size,
                              hipStream_t stream)
{
    const float* x      = (const float*)d_in[0];
    const float* Wfx    = (const float*)d_in[1];
    const float* bfx    = (const float*)d_in[2];
    const float* Wx     = (const float*)d_in[3];
    const float* bx     = (const float*)d_in[4];
    const float* Wslice = (const float*)d_in[5];
    const float* bslice = (const float*)d_in[6];
    const float* temp   = (const float*)d_in[7];
    const float* Wq     = (const float*)d_in[8];
    const float* Wk     = (const float*)d_in[9];
    const float* Wv     = (const float*)d_in[10];
    const float* Wout   = (const float*)d_in[11];
    const float* bout   = (const float*)d_in[12];

    char* ws = (char*)d_ws;
    size_t off = 0;
    auto alloc = [&](size_t bytes) {
        void* p = ws + off;
        off = (off + bytes + 255) & ~(size_t)255;
        return p;
    };
    u16*   fxT   = (u16*)  alloc((size_t)512 * BNc * 2);   // 64 MiB
    u16*   swb   = (u16*)  alloc((size_t)BNc * 256 * 2);   // 32 MiB
    u16*   swT   = (u16*)  alloc((size_t)1024 * Nc * 2);   // 32 MiB
    float* tp    = (float*)alloc((size_t)1024 * 2048 * 4); // 8 MiB
    float* np    = (float*)alloc(32768 * 4);               // 128 KiB
    float* tl    = (float*)alloc(65536 * 4);               // 256 KiB
    float* osl   = (float*)alloc(65536 * 4);               // 256 KiB
    u16*   ZT    = (u16*)  alloc(4 * 65536 * 2);           // 512 KiB
    u16*   WfxT  = (u16*)  alloc(512 * 256 * 2);
    u16*   WxsT  = (u16*)  alloc(256 * 256 * 2);
    float* bxs   = (float*)alloc(256 * 4);

    k0_fold<<<257, 256, 0, stream>>>(Wx, Wslice, bx, bslice, WxsT, bxs);
    kprep_wfx<<<512, 256, 0, stream>>>(Wfx, WfxT);

    // fxT = (x @ Wfx + bfx)^T  bf16 [512][65536]
    kgemm<0><<<dim3(8, 1024), 256, 0, stream>>>(x, WfxT, bfx, nullptr, fxT, nullptr, 256);

    // softmax(x @ Wxs + bxs) -> swb [n][256] + swT [bh*32+g][16384]
    kgemm<1><<<dim3(4, 1024), 256, 0, stream>>>(x, WxsT, bxs, temp, swb, swT, 256);

    k4_token_mfma<<<dim3(32, 32), 256, 0, stream>>>(swT, fxT, tp, np);
    k4b_reduce<<<256, 256, 0, stream>>>(tp, np, tl);
    k5_attn<<<32, 256, 0, stream>>>(tl, Wq, Wk, Wv, osl);
    kZ<<<dim3(4, 16), 256, 0, stream>>>(osl, Wout, ZT);

    // out = swb @ ZT_b^T + bout -> f32 d_out
    kgemm<2><<<dim3(4, 1024), 256, 0, stream>>>(swb, ZT, bout, nullptr, d_out, nullptr, 256);
}

// Round 5
// 383.300 us; speedup vs baseline: 3.5304x; 1.0440x over previous
//
#include <hip/hip_runtime.h>

// Physics_Attention_Irregular_Mesh — round 4
// B=4, N=16384, DIM=256, H=8, D=64, G=32, inner=512. f32 I/O.
// r4 change: the three MFMA GEMMs become single-pass over A (full output
// width per block: 64x512 / 64x256 tiles) -> A streamed from HBM exactly
// once (r3 counters showed 262 MB FETCH vs 131 MB ideal, 44% HBM util).
//   kgemm<0,32> : fxT[c][n] bf16 = (x @ Wfx + bfx)^T
//   kgemm<1,16> : softmax epilogue -> swb[n][256] + swT[bh*32+g][n] bf16
//   kgemm<2,16> : out = swb @ ZT_b^T + bout -> d_out f32
//   k4 : token_part = swT @ fx (MFMA, split-K, direct-global frags)
//   k4b/k5/kZ : reduce+norm, tiny attention, Z = os @ Wout fold

typedef unsigned short u16;
typedef __attribute__((ext_vector_type(8))) unsigned short ushort8v;
typedef __attribute__((ext_vector_type(4))) unsigned short ushort4v;
typedef __attribute__((ext_vector_type(8))) short short8v;
typedef __attribute__((ext_vector_type(4))) float f32x4;

constexpr int Nc = 16384;
constexpr int BNc = 65536;

__device__ inline float b2f(u16 v) {
    union { unsigned int u; float f; } t; t.u = ((unsigned int)v) << 16; return t.f;
}
__device__ inline u16 f2b(float f) {   // round-to-nearest-even
    union { float f; unsigned int u; } t; t.f = f;
    unsigned int u = t.u;
    return (u16)((u + 0x7fffu + ((u >> 16) & 1u)) >> 16);
}

// ---------------- prep: fold WxsT[h*32+g][k] = (Wx_h @ Wslice)^T, bxs ------
__global__ __launch_bounds__(256) void k0_fold(
    const float* __restrict__ Wx, const float* __restrict__ Wslice,
    const float* __restrict__ bx, const float* __restrict__ bslice,
    u16* __restrict__ WxsT, float* __restrict__ bxs)
{
    int blk = blockIdx.x, tid = threadIdx.x;
    int h = tid >> 5, g = tid & 31;
    if (blk < 256) {
        int k = blk;
        float acc = 0.f;
        for (int d = 0; d < 64; d++)
            acc += Wx[k * 512 + h * 64 + d] * Wslice[d * 32 + g];
        WxsT[tid * 256 + k] = f2b(acc);
    } else {
        float acc = 0.f;
        for (int d = 0; d < 64; d++)
            acc += bx[h * 64 + d] * Wslice[d * 32 + g];
        bxs[tid] = acc + bslice[g];
    }
}

// ---------------- prep: WfxT[n][k] bf16 ----------------
__global__ __launch_bounds__(256) void kprep_wfx(const float* __restrict__ Wfx,
                                                 u16* __restrict__ WfxT)
{
    int n = blockIdx.x, k = threadIdx.x;        // 512 blocks x 256
    WfxT[n * 256 + k] = f2b(Wfx[k * 512 + n]);
}

// ------- MFMA GEMM, single-pass: 64 rows x NT*16 cols per block, BK=32. ----
// 4 waves; wave w owns rows [w*16, w*16+16); NT n-tiles of 16.
// Frag layouts: A[m=lane&15][k=quad*8+j], B[k=quad*8+j][n=lane&15],
// D[row=quad*4+r][col=lane&15].
// MODE 0 (NT=32): A=f32 x, Bt=WfxT -> fxT[c][65536] bf16 (+bias), transposed
// MODE 1 (NT=16): A=f32 x, Bt=WxsT, softmax epilogue -> swb + swT
// MODE 2 (NT=16): A=bf16 swb, Bt=ZT (+b*65536) -> f32 [n][256] (+bias)
template <int MODE, int NT>
__global__ __launch_bounds__(256, 2) void kgemm(
    const void* __restrict__ Ap, const u16* __restrict__ Bt,
    const float* __restrict__ bias, const float* __restrict__ temp,
    void* __restrict__ O1, u16* __restrict__ O2)
{
    constexpr int Kd = 256;
    __shared__ u16 Asl[4][64][8];          // [k-chunk][m][j]
    __shared__ u16 Bsl[NT * 16][4][8];     // [n][k-chunk][j]
    int tid = threadIdx.x;
    int wave = tid >> 6, lane = tid & 63;
    int lm = lane & 15, quad = lane >> 4;
    int row0 = blockIdx.x * 64;
    int sm = tid >> 2, skb = tid & 3;
    const u16* BtB = Bt;
    if (MODE == 2) BtB += (size_t)(row0 >> 14) * 65536;
    f32x4 acc[NT] = {};

    for (int k0 = 0; k0 < Kd; k0 += 32) {
        // stage A tile 64x32 -> bf16 LDS
        if (MODE < 2) {
            const float* A32 = (const float*)Ap;
            const f32x4* src = (const f32x4*)(A32 + (size_t)(row0 + sm) * Kd + k0 + skb * 8);
            f32x4 v0 = src[0], v1 = src[1];
            ushort8v o;
#pragma unroll
            for (int j = 0; j < 4; j++) { o[j] = f2b(v0[j]); o[4 + j] = f2b(v1[j]); }
            *(ushort8v*)&Asl[skb][sm][0] = o;
        } else {
            const u16* A16 = (const u16*)Ap;
            *(ushort8v*)&Asl[skb][sm][0] =
                *(const ushort8v*)(A16 + (size_t)(row0 + sm) * Kd + k0 + skb * 8);
        }
        // stage B slice (NT*16 cols x 32 k)
#pragma unroll
        for (int i = 0; i < NT / 4; i++) {
            int e = i * 256 + tid;
            int sn = e >> 2, sk = e & 3;
            *(ushort8v*)&Bsl[sn][sk][0] =
                *(const ushort8v*)(BtB + (size_t)sn * Kd + k0 + sk * 8);
        }
        __syncthreads();
        short8v af = *(short8v*)&Asl[quad][wave * 16 + lm][0];
#pragma unroll
        for (int nt = 0; nt < NT; nt++) {
            short8v bf = *(short8v*)&Bsl[nt * 16 + lm][quad][0];
            acc[nt] = __builtin_amdgcn_mfma_f32_16x16x32_bf16(af, bf, acc[nt], 0, 0, 0);
        }
        __syncthreads();
    }

    if (MODE == 0) {
        u16* fxT = (u16*)O1;
        int nbase = row0 + wave * 16 + quad * 4;
#pragma unroll
        for (int nt = 0; nt < NT; nt++) {
            int c = nt * 16 + lm;
            float bv = bias[c];
            ushort4v o;
#pragma unroll
            for (int r = 0; r < 4; r++) o[r] = f2b(acc[nt][r] + bv);
            *(ushort4v*)(fxT + (size_t)c * 65536 + nbase) = o;
        }
    } else if (MODE == 1) {
        int b = row0 >> 14;
        int nlbase = (row0 & 16383) + wave * 16 + quad * 4;
        u16* swb = (u16*)O1;
#pragma unroll
        for (int h = 0; h < 8; h++) {
            float it = 1.0f / temp[h];
            float bv0 = bias[h * 32 + lm];
            float bv1 = bias[h * 32 + 16 + lm];
            ushort4v p0, p1;
#pragma unroll
            for (int r = 0; r < 4; r++) {
                float v0 = (acc[2 * h][r] + bv0) * it;       // g = lm
                float v1 = (acc[2 * h + 1][r] + bv1) * it;   // g = 16+lm
                float m = fmaxf(v0, v1);
                m = fmaxf(m, __shfl_xor(m, 1));
                m = fmaxf(m, __shfl_xor(m, 2));
                m = fmaxf(m, __shfl_xor(m, 4));
                m = fmaxf(m, __shfl_xor(m, 8));
                float e0 = __expf(v0 - m), e1 = __expf(v1 - m);
                float s = e0 + e1;
                s += __shfl_xor(s, 1);
                s += __shfl_xor(s, 2);
                s += __shfl_xor(s, 4);
                s += __shfl_xor(s, 8);
                float rs = 1.0f / s;
                float w0 = e0 * rs, w1 = e1 * rs;
                int row = row0 + wave * 16 + quad * 4 + r;
                swb[(size_t)row * 256 + h * 32 + lm] = f2b(w0);
                swb[(size_t)row * 256 + h * 32 + 16 + lm] = f2b(w1);
                p0[r] = f2b(w0); p1[r] = f2b(w1);
            }
            size_t gbase = (size_t)((b * 8 + h) * 32);
            *(ushort4v*)(O2 + (gbase + lm) * 16384 + nlbase) = p0;
            *(ushort4v*)(O2 + (gbase + 16 + lm) * 16384 + nlbase) = p1;
        }
    } else {
        float* out = (float*)O1;
#pragma unroll
        for (int nt = 0; nt < NT; nt++) {
            int c = nt * 16 + lm;
            float bv = bias[c];
#pragma unroll
            for (int r = 0; r < 4; r++)
                out[(size_t)(row0 + wave * 16 + quad * 4 + r) * 256 + c] = acc[nt][r] + bv;
        }
    }
}

// ---------------- k4: token pooling via MFMA, split-K ----------------
__global__ __launch_bounds__(256) void k4_token_mfma(
    const u16* __restrict__ swT, const u16* __restrict__ fxT,
    float* __restrict__ token_part, float* __restrict__ norm_part)
{
    int bh = blockIdx.x, ky = blockIdx.y;
    int b = bh >> 3, h = bh & 7;
    int tid = threadIdx.x, wave = tid >> 6, lane = tid & 63;
    int lm = lane & 15, quad = lane >> 4;
    int mt = wave & 1, dp = wave >> 1;
    const u16* Ar = swT + ((size_t)(bh * 32 + mt * 16 + lm)) * 16384 + ky * 512 + quad * 8;
    const u16* Br0 = fxT + ((size_t)(h * 64 + dp * 32 + lm)) * 65536
                     + (size_t)b * 16384 + ky * 512 + quad * 8;
    const u16* Br1 = Br0 + (size_t)16 * 65536;
    f32x4 acc0 = {}, acc1 = {};
    float nacc = 0.f;
#pragma unroll
    for (int kk = 0; kk < 16; kk++) {
        short8v af = *(const short8v*)(Ar + kk * 32);
        short8v b0 = *(const short8v*)(Br0 + kk * 32);
        short8v b1 = *(const short8v*)(Br1 + kk * 32);
        acc0 = __builtin_amdgcn_mfma_f32_16x16x32_bf16(af, b0, acc0, 0, 0, 0);
        acc1 = __builtin_amdgcn_mfma_f32_16x16x32_bf16(af, b1, acc1, 0, 0, 0);
        if (dp == 0) {
            ushort8v au = (ushort8v&)af;
#pragma unroll
            for (int j = 0; j < 8; j++) nacc += b2f(au[j]);
        }
    }
    float* tp = token_part + ((size_t)(ky * 32 + bh)) * 2048;
#pragma unroll
    for (int r = 0; r < 4; r++) {
        int g = mt * 16 + quad * 4 + r;
        tp[g * 64 + dp * 32 + lm] = acc0[r];
        tp[g * 64 + dp * 32 + 16 + lm] = acc1[r];
    }
    if (dp == 0) {
        nacc += __shfl_xor(nacc, 16);
        nacc += __shfl_xor(nacc, 32);
        if (lane < 16)
            norm_part[(ky * 32 + bh) * 32 + mt * 16 + lm] = nacc;
    }
}

// ---------------- k4b: reduce partials -> tl = token/(norm+1e-5) ----------
__global__ __launch_bounds__(256) void k4b_reduce(
    const float* __restrict__ tp, const float* __restrict__ np,
    float* __restrict__ tl)
{
    int t = blockIdx.x * 256 + threadIdx.x;   // 65536
    int bh = t >> 11, e = t & 2047, g = e >> 6;
    float ts = 0.f, ns = 0.f;
    for (int ch = 0; ch < 32; ch++) {
        ts += tp[((size_t)(ch * 32 + bh)) * 2048 + e];
        ns += np[(ch * 32 + bh) * 32 + g];
    }
    tl[t] = ts / (ns + 1e-5f);
}

// ---------------- k5: tiny attention over G tokens ----------------
__global__ __launch_bounds__(256) void k5_attn(
    const float* __restrict__ tlg,
    const float* __restrict__ Wq, const float* __restrict__ Wk, const float* __restrict__ Wv,
    float* __restrict__ out_slice)
{
    __shared__ float tl[32][64];
    __shared__ float ql[32][64], kl[32][64], vl[32][64];
    __shared__ float sl[32][33];
    int bh = blockIdx.x, tid = threadIdx.x;
    const float* tk = tlg + (size_t)bh * 2048;

#pragma unroll
    for (int j = 0; j < 8; j++) {
        int idx = j * 256 + tid;
        tl[idx >> 6][idx & 63] = tk[idx];
    }
    __syncthreads();
#pragma unroll
    for (int j = 0; j < 8; j++) {
        int idx = j * 256 + tid;
        int g = idx >> 6, d = idx & 63;
        float aq = 0.f, ak = 0.f, av = 0.f;
        for (int e = 0; e < 64; e++) {
            float t = tl[g][e];
            aq += t * Wq[e * 64 + d];
            ak += t * Wk[e * 64 + d];
            av += t * Wv[e * 64 + d];
        }
        ql[g][d] = aq; kl[g][d] = ak; vl[g][d] = av;
    }
    __syncthreads();
#pragma unroll
    for (int j = 0; j < 4; j++) {
        int idx = j * 256 + tid;
        int gq = idx >> 5, gk = idx & 31;
        float s = 0.f;
        for (int d = 0; d < 64; d++) s += ql[gq][d] * kl[gk][d];
        sl[gq][gk] = s * 0.125f;   // 1/sqrt(64)
    }
    __syncthreads();
    if (tid < 32) {
        float m = -1e30f;
        for (int k2 = 0; k2 < 32; k2++) m = fmaxf(m, sl[tid][k2]);
        float s = 0.f;
        for (int k2 = 0; k2 < 32; k2++) { float e = __expf(sl[tid][k2] - m); sl[tid][k2] = e; s += e; }
        float r = 1.0f / s;
        for (int k2 = 0; k2 < 32; k2++) sl[tid][k2] *= r;
    }
    __syncthreads();
#pragma unroll
    for (int j = 0; j < 8; j++) {
        int idx = j * 256 + tid;
        int g = idx >> 6, d = idx & 63;
        float a = 0.f;
        for (int k2 = 0; k2 < 32; k2++) a += sl[g][k2] * vl[k2][d];
        out_slice[(size_t)bh * 2048 + idx] = a;
    }
}

// ---------------- kZ: ZT[b][c][hg] = (os_bh @ Wout_h)^T, bf16 -------------
__global__ __launch_bounds__(256) void kZ(
    const float* __restrict__ os, const float* __restrict__ Wout,
    u16* __restrict__ ZT)
{
    int b = blockIdx.x, cb = blockIdx.y;   // grid (4, 16)
    int t = threadIdx.x;
    int c = cb * 16 + (t & 15), kq = t >> 4;
    for (int k = kq * 16; k < kq * 16 + 16; k++) {
        int h = k >> 5, g = k & 31;
        const float* osr = os + ((size_t)(b * 8 + h)) * 2048 + g * 64;
        float acc = 0.f;
        for (int d = 0; d < 64; d++)
            acc += osr[d] * Wout[(h * 64 + d) * 256 + c];
        ZT[(size_t)b * 65536 + c * 256 + k] = f2b(acc);
    }
}

// ---------------- launcher ----------------
extern "C" void kernel_launch(void* const* d_in, const int* in_sizes, int n_in,
                              void* d_out, int out_size, void* d_ws, size_t ws_size,
                              hipStream_t stream)
{
    const float* x      = (const float*)d_in[0];
    const float* Wfx    = (const float*)d_in[1];
    const float* bfx    = (const float*)d_in[2];
    const float* Wx     = (const float*)d_in[3];
    const float* bx     = (const float*)d_in[4];
    const float* Wslice = (const float*)d_in[5];
    const float* bslice = (const float*)d_in[6];
    const float* temp   = (const float*)d_in[7];
    const float* Wq     = (const float*)d_in[8];
    const float* Wk     = (const float*)d_in[9];
    const float* Wv     = (const float*)d_in[10];
    const float* Wout   = (const float*)d_in[11];
    const float* bout   = (const float*)d_in[12];

    char* ws = (char*)d_ws;
    size_t off = 0;
    auto alloc = [&](size_t bytes) {
        void* p = ws + off;
        off = (off + bytes + 255) & ~(size_t)255;
        return p;
    };
    u16*   fxT   = (u16*)  alloc((size_t)512 * BNc * 2);   // 64 MiB
    u16*   swb   = (u16*)  alloc((size_t)BNc * 256 * 2);   // 32 MiB
    u16*   swT   = (u16*)  alloc((size_t)1024 * Nc * 2);   // 32 MiB
    float* tp    = (float*)alloc((size_t)1024 * 2048 * 4); // 8 MiB
    float* np    = (float*)alloc(32768 * 4);               // 128 KiB
    float* tl    = (float*)alloc(65536 * 4);               // 256 KiB
    float* osl   = (float*)alloc(65536 * 4);               // 256 KiB
    u16*   ZT    = (u16*)  alloc(4 * 65536 * 2);           // 512 KiB
    u16*   WfxT  = (u16*)  alloc(512 * 256 * 2);
    u16*   WxsT  = (u16*)  alloc(256 * 256 * 2);
    float* bxs   = (float*)alloc(256 * 4);

    k0_fold<<<257, 256, 0, stream>>>(Wx, Wslice, bx, bslice, WxsT, bxs);
    kprep_wfx<<<512, 256, 0, stream>>>(Wfx, WfxT);

    // fxT = (x @ Wfx + bfx)^T  bf16 [512][65536]  — single pass over x
    kgemm<0, 32><<<1024, 256, 0, stream>>>(x, WfxT, bfx, nullptr, fxT, nullptr);

    // softmax(x @ Wxs + bxs) -> swb [n][256] + swT [bh*32+g][16384]
    kgemm<1, 16><<<1024, 256, 0, stream>>>(x, WxsT, bxs, temp, swb, swT);

    k4_token_mfma<<<dim3(32, 32), 256, 0, stream>>>(swT, fxT, tp, np);
    k4b_reduce<<<256, 256, 0, stream>>>(tp, np, tl);
    k5_attn<<<32, 256, 0, stream>>>(tl, Wq, Wk, Wv, osl);
    kZ<<<dim3(4, 16), 256, 0, stream>>>(osl, Wout, ZT);

    // out = swb @ ZT_b^T + bout -> f32 d_out
    kgemm<2, 16><<<1024, 256, 0, stream>>>(swb, ZT, bout, nullptr, d_out, nullptr);
}